// Round 1
// baseline (155.192 us; speedup 1.0000x reference)
//
#include <hip/hip_runtime.h>
#include <math.h>

// Problem dims (fixed by setup_inputs): B=8, C=256, H=64, W=64, fp32.
#define BB 8
#define CC 256
#define HH 64
#define WW 64
#define EPS 1e-5f

// ---------------------------------------------------------------------------
// P1: block per (b,c). Computes z1[b,c,w] = max/mean over h, and
//     z2[b,h,c] = max/mean over w.  LDS tile padded to 65 to kill conflicts.
// ---------------------------------------------------------------------------
__global__ __launch_bounds__(256) void pool_hw_kernel(
    const float* __restrict__ x,
    float* __restrict__ z1max, float* __restrict__ z1mean,
    float* __restrict__ z2max, float* __restrict__ z2mean)
{
    int bc = blockIdx.x;               // b*256 + c
    int b = bc >> 8, c = bc & 255;
    const float* xt = x + (size_t)bc * (HH * WW);

    __shared__ float tile[HH * 65];
    __shared__ float red[512];         // [0:256) max partials, [256:512) sum partials
    int t = threadIdx.x;

    for (int i = t; i < HH * WW; i += 256) {
        int h = i >> 6, w = i & 63;
        tile[h * 65 + w] = xt[i];
    }
    __syncthreads();

    // Phase A: reduce over h (per w). t = hg*64 + w
    {
        int w = t & 63, hg = t >> 6;
        float m = -INFINITY, s = 0.f;
        #pragma unroll
        for (int i = 0; i < 16; ++i) {
            float v = tile[(hg * 16 + i) * 65 + w];
            m = fmaxf(m, v); s += v;
        }
        red[t] = m; red[256 + t] = s;
    }
    __syncthreads();
    if (t < 64) {
        int w = t;
        float m = red[w], s = red[256 + w];
        #pragma unroll
        for (int g = 1; g < 4; ++g) { m = fmaxf(m, red[g * 64 + w]); s += red[256 + g * 64 + w]; }
        z1max [bc * WW + w] = m;
        z1mean[bc * WW + w] = s * (1.f / 64.f);
    }
    __syncthreads();

    // Phase B: reduce over w (per h). t = wg*64 + h
    {
        int h = t & 63, wg = t >> 6;
        float m = -INFINITY, s = 0.f;
        #pragma unroll
        for (int i = 0; i < 16; ++i) {
            float v = tile[h * 65 + wg * 16 + i];
            m = fmaxf(m, v); s += v;
        }
        red[t] = m; red[256 + t] = s;
    }
    __syncthreads();
    if (t < 64) {
        int h = t;
        float m = red[h], s = red[256 + h];
        #pragma unroll
        for (int g = 1; g < 4; ++g) { m = fmaxf(m, red[g * 64 + h]); s += red[256 + g * 64 + h]; }
        z2max [(b * HH + h) * CC + c] = m;       // layout [B,H,C]
        z2mean[(b * HH + h) * CC + c] = s * (1.f / 64.f);
    }
}

// ---------------------------------------------------------------------------
// P2: block per (b,h). z3[b,h,w] = max/mean over c.
//     256 threads = 4 c-groups x 64 w lanes (coalesced 256B per c step).
// ---------------------------------------------------------------------------
__global__ __launch_bounds__(256) void pool_c_kernel(
    const float* __restrict__ x,
    float* __restrict__ z3max, float* __restrict__ z3mean)
{
    int bh = blockIdx.x;               // b*64 + h
    int b = bh >> 6, h = bh & 63;
    int t = threadIdx.x;
    int w = t & 63, cg = t >> 6;

    const float* base = x + ((size_t)b * CC * HH + h) * WW + w;   // c stride = H*W
    float m = -INFINITY, s = 0.f;
    #pragma unroll 4
    for (int i = 0; i < 64; ++i) {
        float v = base[(size_t)(cg * 64 + i) * (HH * WW)];
        m = fmaxf(m, v); s += v;
    }
    __shared__ float red[512];
    red[t] = m; red[256 + t] = s;
    __syncthreads();
    if (t < 64) {
        #pragma unroll
        for (int g = 1; g < 4; ++g) { m = fmaxf(m, red[g * 64 + w]); s += red[256 + g * 64 + w]; }
        z3max [bh * WW + w] = m;
        z3mean[bh * WW + w] = s * (1.f / 256.f);
    }
}

// ---------------------------------------------------------------------------
// Fused 7x7 conv (2ch -> 1) + inference BN + sigmoid, for all 3 branches.
// blockIdx.y selects branch: 0 -> plane [C,W], 1 -> [H,C], 2 -> [H,W].
// ---------------------------------------------------------------------------
__global__ __launch_bounds__(256) void conv_gate_kernel(
    const float* __restrict__ z1max, const float* __restrict__ z1mean,
    const float* __restrict__ w0p, const float* g0, const float* b0,
    const float* m0, const float* v0, float* __restrict__ s1,
    const float* __restrict__ z2max, const float* __restrict__ z2mean,
    const float* __restrict__ w1p, const float* g1, const float* b1,
    const float* m1, const float* v1, float* __restrict__ s2,
    const float* __restrict__ z3max, const float* __restrict__ z3mean,
    const float* __restrict__ w2p, const float* g2, const float* b2,
    const float* m2, const float* v2, float* __restrict__ s3)
{
    int br = blockIdx.y;
    const float *zm, *za, *wp, *gp, *bp, *mp, *vp;
    float* sp; int R, Cw;
    if (br == 0)      { zm=z1max; za=z1mean; wp=w0p; gp=g0; bp=b0; mp=m0; vp=v0; sp=s1; R=CC; Cw=WW; }
    else if (br == 1) { zm=z2max; za=z2mean; wp=w1p; gp=g1; bp=b1; mp=m1; vp=v1; sp=s2; R=HH; Cw=CC; }
    else              { zm=z3max; za=z3mean; wp=w2p; gp=g2; bp=b2; mp=m2; vp=v2; sp=s3; R=HH; Cw=WW; }

    int total = BB * R * Cw;
    int o = blockIdx.x * 256 + threadIdx.x;
    if (o >= total) return;

    int b   = o / (R * Cw);
    int rem = o - b * R * Cw;
    int r   = rem / Cw;
    int col = rem - r * Cw;

    const float* zmb = zm + (size_t)b * R * Cw;
    const float* zab = za + (size_t)b * R * Cw;

    float acc = 0.f;
    #pragma unroll
    for (int dr = 0; dr < 7; ++dr) {
        int rr = r + dr - 3;
        if (rr < 0 || rr >= R) continue;
        #pragma unroll
        for (int dc = 0; dc < 7; ++dc) {
            int cc = col + dc - 3;
            if (cc < 0 || cc >= Cw) continue;
            float wm = wp[dr * 7 + dc];        // channel 0 = max
            float wa = wp[49 + dr * 7 + dc];   // channel 1 = mean
            acc += wm * zmb[rr * Cw + cc] + wa * zab[rr * Cw + cc];
        }
    }
    float scale = gp[0] * rsqrtf(vp[0] + EPS);
    float y = (acc - mp[0]) * scale + bp[0];
    sp[o] = 1.f / (1.f + __expf(-y));
}

// ---------------------------------------------------------------------------
// pooled[b,c] = (1/3) * mean_{h,w} x[b,c,h,w]*(s1[b,c,w]+s2[b,h,c]+s3[b,h,w])
// Block per (b,c): 256 threads = 4 h-groups x 64 w lanes.
// ---------------------------------------------------------------------------
__global__ __launch_bounds__(256) void pooled_kernel(
    const float* __restrict__ x,
    const float* __restrict__ s1, const float* __restrict__ s2,
    const float* __restrict__ s3, float* __restrict__ pooled)
{
    int bc = blockIdx.x;
    int b = bc >> 8, c = bc & 255;
    int t = threadIdx.x;
    int w = t & 63, hg = t >> 6;

    const float* xt  = x  + (size_t)bc * (HH * WW);
    float s1v        = s1[bc * WW + w];
    const float* s2b = s2 + (size_t)b * HH * CC + c;   // + h*CC
    const float* s3b = s3 + (size_t)b * HH * WW + w;   // + h*WW

    float acc = 0.f;
    #pragma unroll 4
    for (int i = 0; i < 16; ++i) {
        int h = hg * 16 + i;
        acc += xt[h * WW + w] * (s1v + s2b[h * CC] + s3b[h * WW]);
    }
    // wave64 reduce, then cross-wave via LDS
    #pragma unroll
    for (int off = 32; off >= 1; off >>= 1) acc += __shfl_down(acc, off);
    __shared__ float r[4];
    if ((t & 63) == 0) r[t >> 6] = acc;
    __syncthreads();
    if (t == 0) pooled[bc] = (r[0] + r[1] + r[2] + r[3]) * (1.f / (4096.f * 3.f));
}

// ---------------------------------------------------------------------------
// logits[b,k,c] = conv1d(pooled, w1d, pad 3); wts = softmax over k. [B,3,C]
// ---------------------------------------------------------------------------
__global__ __launch_bounds__(256) void wts_kernel(
    const float* __restrict__ pooled, const float* __restrict__ w1d,
    float* __restrict__ wts)
{
    int o = blockIdx.x * 256 + threadIdx.x;
    if (o >= BB * CC) return;
    int b = o >> 8, c = o & 255;
    const float* p = pooled + b * CC;

    float lg[3];
    #pragma unroll
    for (int k = 0; k < 3; ++k) {
        float a = 0.f;
        #pragma unroll
        for (int j = 0; j < 7; ++j) {
            int cc = c + j - 3;
            if (cc >= 0 && cc < CC) a += w1d[k * 7 + j] * p[cc];
        }
        lg[k] = a;
    }
    float mx = fmaxf(lg[0], fmaxf(lg[1], lg[2]));
    float e0 = __expf(lg[0] - mx), e1 = __expf(lg[1] - mx), e2 = __expf(lg[2] - mx);
    float inv = 1.f / (e0 + e1 + e2);
    wts[(b * 3 + 0) * CC + c] = e0 * inv;
    wts[(b * 3 + 1) * CC + c] = e1 * inv;
    wts[(b * 3 + 2) * CC + c] = e2 * inv;
}

// ---------------------------------------------------------------------------
// out = x * (k0*s1[b,c,w] + k1*s2[b,h,c] + k2*s3[b,h,w]); float4 per thread.
// ---------------------------------------------------------------------------
__global__ __launch_bounds__(256) void final_kernel(
    const float* __restrict__ x,
    const float* __restrict__ s1, const float* __restrict__ s2,
    const float* __restrict__ s3, const float* __restrict__ wts,
    float* __restrict__ out)
{
    int i4 = blockIdx.x * 256 + threadIdx.x;      // element/4 index
    int w0   = (i4 & 15) * 4;
    int rest = i4 >> 4;
    int h = rest & 63; rest >>= 6;
    int c = rest & 255;
    int b = rest >> 8;

    const float4 x4  = *(const float4*)(x  + (size_t)i4 * 4);
    const float4 s1v = *(const float4*)(s1 + ((size_t)(b * CC + c)) * WW + w0);
    const float  s2v = s2[(b * HH + h) * CC + c];
    const float4 s3v = *(const float4*)(s3 + ((size_t)(b * HH + h)) * WW + w0);
    float k0 = wts[(b * 3 + 0) * CC + c];
    float k1 = wts[(b * 3 + 1) * CC + c];
    float k2 = wts[(b * 3 + 2) * CC + c];

    float4 o;
    o.x = x4.x * (k0 * s1v.x + k1 * s2v + k2 * s3v.x);
    o.y = x4.y * (k0 * s1v.y + k1 * s2v + k2 * s3v.y);
    o.z = x4.z * (k0 * s1v.z + k1 * s2v + k2 * s3v.z);
    o.w = x4.w * (k0 * s1v.w + k1 * s2v + k2 * s3v.w);
    *(float4*)(out + (size_t)i4 * 4) = o;
}

// ---------------------------------------------------------------------------
extern "C" void kernel_launch(void* const* d_in, const int* in_sizes, int n_in,
                              void* d_out, int out_size, void* d_ws, size_t ws_size,
                              hipStream_t stream)
{
    const float* x    = (const float*)d_in[0];
    const float* w_cw = (const float*)d_in[1];
    const float* g_cw = (const float*)d_in[2];
    const float* b_cw = (const float*)d_in[3];
    const float* m_cw = (const float*)d_in[4];
    const float* v_cw = (const float*)d_in[5];
    const float* w_hc = (const float*)d_in[6];
    const float* g_hc = (const float*)d_in[7];
    const float* b_hc = (const float*)d_in[8];
    const float* m_hc = (const float*)d_in[9];
    const float* v_hc = (const float*)d_in[10];
    const float* w_hw = (const float*)d_in[11];
    const float* g_hw = (const float*)d_in[12];
    const float* b_hw = (const float*)d_in[13];
    const float* m_hw = (const float*)d_in[14];
    const float* v_hw = (const float*)d_in[15];
    const float* w1d  = (const float*)d_in[16];
    float* out = (float*)d_out;

    // Workspace layout (floats)
    float* ws = (float*)d_ws;
    const size_t N1 = (size_t)BB * CC * WW;   // 131072  z1/s1 [B,C,W]
    const size_t N2 = (size_t)BB * HH * CC;   // 131072  z2/s2 [B,H,C]
    const size_t N3 = (size_t)BB * HH * WW;   // 32768   z3/s3 [B,H,W]
    float* z1max  = ws;
    float* z1mean = z1max  + N1;
    float* z2max  = z1mean + N1;
    float* z2mean = z2max  + N2;
    float* z3max  = z2mean + N2;
    float* z3mean = z3max  + N3;
    float* s1     = z3mean + N3;
    float* s2     = s1 + N1;
    float* s3     = s2 + N2;
    float* pooled = s3 + N3;                  // B*C = 2048
    float* wts    = pooled + (size_t)BB * CC; // B*3*C = 6144

    pool_hw_kernel<<<BB * CC, 256, 0, stream>>>(x, z1max, z1mean, z2max, z2mean);
    pool_c_kernel <<<BB * HH, 256, 0, stream>>>(x, z3max, z3mean);

    conv_gate_kernel<<<dim3((BB * CC * WW + 255) / 256, 3), 256, 0, stream>>>(
        z1max, z1mean, w_cw, g_cw, b_cw, m_cw, v_cw, s1,
        z2max, z2mean, w_hc, g_hc, b_hc, m_hc, v_hc, s2,
        z3max, z3mean, w_hw, g_hw, b_hw, m_hw, v_hw, s3);

    pooled_kernel<<<BB * CC, 256, 0, stream>>>(x, s1, s2, s3, pooled);
    wts_kernel<<<(BB * CC + 255) / 256, 256, 0, stream>>>(pooled, w1d, wts);

    final_kernel<<<(BB * CC * HH * WW / 4 + 255) / 256, 256, 0, stream>>>(
        x, s1, s2, s3, wts, out);
}

// Round 2
// 150.529 us; speedup vs baseline: 1.0310x; 1.0310x over previous
//
#include <hip/hip_runtime.h>
#include <math.h>

// Problem dims (fixed by setup_inputs): B=8, C=256, H=64, W=64, fp32.
#define BB 8
#define CC 256
#define HH 64
#define WW 64
#define EPS 1e-5f

// ---------------------------------------------------------------------------
// Fused pooling: one x pass.
//   blocks [0,2048):   bc = blk. z1[b,c,w] = max/mean over h; z2[b,h,c] = over w.
//   blocks [2048,2560): bh = blk-2048. z3[b,h,w] = max/mean over c.
// ---------------------------------------------------------------------------
__global__ __launch_bounds__(256) void pool_kernel(
    const float* __restrict__ x,
    float* __restrict__ z1max, float* __restrict__ z1mean,
    float* __restrict__ z2max, float* __restrict__ z2mean,
    float* __restrict__ z3max, float* __restrict__ z3mean)
{
    __shared__ float smem[HH * 65 + 512];      // 18688 B, aliased by both halves
    int blk = blockIdx.x;
    int t = threadIdx.x;

    if (blk < BB * CC) {
        // ---- per-(b,c) pools over h and over w ----
        int bc = blk;
        int b = bc >> 8, c = bc & 255;
        const float4* xt4 = (const float4*)x + (size_t)bc * 1024;
        float* tile = smem;                    // [64][65]
        float* red  = smem + HH * 65;          // [512]

        #pragma unroll
        for (int i = 0; i < 4; ++i) {
            int idx = t + i * 256;             // float4 index in tile
            float4 v = xt4[idx];
            int h = idx >> 4, w0 = (idx & 15) * 4;
            float* d = &tile[h * 65 + w0];
            d[0] = v.x; d[1] = v.y; d[2] = v.z; d[3] = v.w;
        }
        __syncthreads();

        // Phase A: reduce over h (per w). t = hg*64 + w
        {
            int w = t & 63, hg = t >> 6;
            float m = -INFINITY, s = 0.f;
            #pragma unroll
            for (int i = 0; i < 16; ++i) {
                float v = tile[(hg * 16 + i) * 65 + w];
                m = fmaxf(m, v); s += v;
            }
            red[t] = m; red[256 + t] = s;
        }
        __syncthreads();
        if (t < 64) {
            int w = t;
            float m = red[w], s = red[256 + w];
            #pragma unroll
            for (int g = 1; g < 4; ++g) { m = fmaxf(m, red[g * 64 + w]); s += red[256 + g * 64 + w]; }
            z1max [bc * WW + w] = m;
            z1mean[bc * WW + w] = s * (1.f / 64.f);
        }
        __syncthreads();

        // Phase B: reduce over w (per h). t = wg*64 + h
        {
            int h = t & 63, wg = t >> 6;
            float m = -INFINITY, s = 0.f;
            #pragma unroll
            for (int i = 0; i < 16; ++i) {
                float v = tile[h * 65 + wg * 16 + i];
                m = fmaxf(m, v); s += v;
            }
            red[t] = m; red[256 + t] = s;
        }
        __syncthreads();
        if (t < 64) {
            int h = t;
            float m = red[h], s = red[256 + h];
            #pragma unroll
            for (int g = 1; g < 4; ++g) { m = fmaxf(m, red[g * 64 + h]); s += red[256 + g * 64 + h]; }
            z2max [(b * HH + h) * CC + c] = m;
            z2mean[(b * HH + h) * CC + c] = s * (1.f / 64.f);
        }
    } else {
        // ---- per-(b,h) pool over c, float4 over w ----
        int bh = blk - BB * CC;
        int b = bh >> 6, h = bh & 63;
        int wq = t & 15, cg = t >> 4;          // 16 w-quads x 16 c-groups

        const float4* base = (const float4*)x
            + ((size_t)b * CC * HH * WW + (size_t)h * WW) / 4 + wq;
        float4 m = make_float4(-INFINITY, -INFINITY, -INFINITY, -INFINITY);
        float4 s = make_float4(0.f, 0.f, 0.f, 0.f);
        #pragma unroll 4
        for (int i = 0; i < 16; ++i) {
            float4 v = base[(size_t)(cg * 16 + i) * 1024];   // c stride = H*W/4 float4
            m.x = fmaxf(m.x, v.x); m.y = fmaxf(m.y, v.y);
            m.z = fmaxf(m.z, v.z); m.w = fmaxf(m.w, v.w);
            s.x += v.x; s.y += v.y; s.z += v.z; s.w += v.w;
        }
        float4* mred = (float4*)smem;          // [256]
        float4* sred = (float4*)smem + 256;    // [256]
        mred[t] = m; sred[t] = s;
        __syncthreads();
        if (t < 16) {
            float4 mm = mred[t], ss = sred[t];
            #pragma unroll
            for (int g = 1; g < 16; ++g) {
                float4 mv = mred[g * 16 + t], sv = sred[g * 16 + t];
                mm.x = fmaxf(mm.x, mv.x); mm.y = fmaxf(mm.y, mv.y);
                mm.z = fmaxf(mm.z, mv.z); mm.w = fmaxf(mm.w, mv.w);
                ss.x += sv.x; ss.y += sv.y; ss.z += sv.z; ss.w += sv.w;
            }
            ss.x *= (1.f / 256.f); ss.y *= (1.f / 256.f);
            ss.z *= (1.f / 256.f); ss.w *= (1.f / 256.f);
            *(float4*)(z3max  + bh * WW + t * 4) = mm;
            *(float4*)(z3mean + bh * WW + t * 4) = ss;
        }
    }
}

// ---------------------------------------------------------------------------
// Fused 7x7 conv (2ch -> 1) + inference BN + sigmoid, for all 3 branches.
// blockIdx.y selects branch: 0 -> plane [C,W], 1 -> [H,C], 2 -> [H,W].
// ---------------------------------------------------------------------------
__global__ __launch_bounds__(256) void conv_gate_kernel(
    const float* __restrict__ z1max, const float* __restrict__ z1mean,
    const float* __restrict__ w0p, const float* g0, const float* b0,
    const float* m0, const float* v0, float* __restrict__ s1,
    const float* __restrict__ z2max, const float* __restrict__ z2mean,
    const float* __restrict__ w1p, const float* g1, const float* b1,
    const float* m1, const float* v1, float* __restrict__ s2,
    const float* __restrict__ z3max, const float* __restrict__ z3mean,
    const float* __restrict__ w2p, const float* g2, const float* b2,
    const float* m2, const float* v2, float* __restrict__ s3)
{
    int br = blockIdx.y;
    const float *zm, *za, *wp, *gp, *bp, *mp, *vp;
    float* sp; int R, Cw;
    if (br == 0)      { zm=z1max; za=z1mean; wp=w0p; gp=g0; bp=b0; mp=m0; vp=v0; sp=s1; R=CC; Cw=WW; }
    else if (br == 1) { zm=z2max; za=z2mean; wp=w1p; gp=g1; bp=b1; mp=m1; vp=v1; sp=s2; R=HH; Cw=CC; }
    else              { zm=z3max; za=z3mean; wp=w2p; gp=g2; bp=b2; mp=m2; vp=v2; sp=s3; R=HH; Cw=WW; }

    int total = BB * R * Cw;
    int o = blockIdx.x * 256 + threadIdx.x;
    if (o >= total) return;

    int b   = o / (R * Cw);
    int rem = o - b * R * Cw;
    int r   = rem / Cw;
    int col = rem - r * Cw;

    const float* zmb = zm + (size_t)b * R * Cw;
    const float* zab = za + (size_t)b * R * Cw;

    float acc = 0.f;
    #pragma unroll
    for (int dr = 0; dr < 7; ++dr) {
        int rr = r + dr - 3;
        if (rr < 0 || rr >= R) continue;
        #pragma unroll
        for (int dc = 0; dc < 7; ++dc) {
            int cc = col + dc - 3;
            if (cc < 0 || cc >= Cw) continue;
            float wm = wp[dr * 7 + dc];        // channel 0 = max
            float wa = wp[49 + dr * 7 + dc];   // channel 1 = mean
            acc += wm * zmb[rr * Cw + cc] + wa * zab[rr * Cw + cc];
        }
    }
    float scale = gp[0] * rsqrtf(vp[0] + EPS);
    float y = (acc - mp[0]) * scale + bp[0];
    sp[o] = 1.f / (1.f + __expf(-y));
}

// ---------------------------------------------------------------------------
// pooled[b,c] = (1/3)*mean_{h,w} x*(s1+s2+s3)
//            = (Σ_{h,w} x*s3 + 64*Σ_w s1*z1mean + 64*Σ_h s2*z2mean) / 12288
// Block per (b,c); x and s3 read as float4.
// ---------------------------------------------------------------------------
__global__ __launch_bounds__(256) void pooled_kernel(
    const float* __restrict__ x,
    const float* __restrict__ s1, const float* __restrict__ z1mean,
    const float* __restrict__ s2, const float* __restrict__ z2mean,
    const float* __restrict__ s3, float* __restrict__ pooled)
{
    int bc = blockIdx.x;
    int b = bc >> 8, c = bc & 255;
    int t = threadIdx.x;

    const float4* xt4 = (const float4*)x  + (size_t)bc * 1024;
    const float4* s34 = (const float4*)s3 + (size_t)b * 1024;

    float acc = 0.f;
    #pragma unroll
    for (int i = 0; i < 4; ++i) {
        float4 xv = xt4[t + i * 256];
        float4 sv = s34[t + i * 256];
        acc += xv.x * sv.x + xv.y * sv.y + xv.z * sv.z + xv.w * sv.w;
    }
    if (t < 64) {
        int w = t;
        acc += 64.f * s1[bc * WW + w] * z1mean[bc * WW + w];
    } else if (t < 128) {
        int h = t - 64;
        int idx = (b * HH + h) * CC + c;
        acc += 64.f * s2[idx] * z2mean[idx];
    }
    #pragma unroll
    for (int off = 32; off >= 1; off >>= 1) acc += __shfl_down(acc, off);
    __shared__ float r[4];
    if ((t & 63) == 0) r[t >> 6] = acc;
    __syncthreads();
    if (t == 0) pooled[bc] = (r[0] + r[1] + r[2] + r[3]) * (1.f / (4096.f * 3.f));
}

// ---------------------------------------------------------------------------
// out = x * (k0*s1[b,c,w] + k1*s2[b,h,c] + k2*s3[b,h,w])
// softmax weights computed inline from pooled (7 loads, wave-uniform).
// ---------------------------------------------------------------------------
__global__ __launch_bounds__(256) void final_kernel(
    const float* __restrict__ x,
    const float* __restrict__ s1, const float* __restrict__ s2,
    const float* __restrict__ s3, const float* __restrict__ pooled,
    const float* __restrict__ w1d, float* __restrict__ out)
{
    int i4 = blockIdx.x * 256 + threadIdx.x;      // element/4 index
    int w0   = (i4 & 15) * 4;
    int rest = i4 >> 4;
    int h = rest & 63; rest >>= 6;
    int c = rest & 255;
    int b = rest >> 8;

    // conv1d(pooled) + softmax over k (zero-padded at c boundaries)
    float lg0 = 0.f, lg1 = 0.f, lg2 = 0.f;
    #pragma unroll
    for (int j = 0; j < 7; ++j) {
        int cc = c + j - 3;
        float p = (cc >= 0 && cc < CC) ? pooled[b * CC + cc] : 0.f;
        lg0 += w1d[j] * p;
        lg1 += w1d[7 + j] * p;
        lg2 += w1d[14 + j] * p;
    }
    float mx = fmaxf(lg0, fmaxf(lg1, lg2));
    float e0 = __expf(lg0 - mx), e1 = __expf(lg1 - mx), e2 = __expf(lg2 - mx);
    float inv = 1.f / (e0 + e1 + e2);
    float k0 = e0 * inv, k1 = e1 * inv, k2 = e2 * inv;

    const float4 x4  = *(const float4*)(x  + (size_t)i4 * 4);
    const float4 s1v = *(const float4*)(s1 + ((size_t)(b * CC + c)) * WW + w0);
    const float  s2v = s2[(b * HH + h) * CC + c];
    const float4 s3v = *(const float4*)(s3 + ((size_t)(b * HH + h)) * WW + w0);

    float4 o;
    o.x = x4.x * (k0 * s1v.x + k1 * s2v + k2 * s3v.x);
    o.y = x4.y * (k0 * s1v.y + k1 * s2v + k2 * s3v.y);
    o.z = x4.z * (k0 * s1v.z + k1 * s2v + k2 * s3v.z);
    o.w = x4.w * (k0 * s1v.w + k1 * s2v + k2 * s3v.w);
    *(float4*)(out + (size_t)i4 * 4) = o;
}

// ---------------------------------------------------------------------------
extern "C" void kernel_launch(void* const* d_in, const int* in_sizes, int n_in,
                              void* d_out, int out_size, void* d_ws, size_t ws_size,
                              hipStream_t stream)
{
    const float* x    = (const float*)d_in[0];
    const float* w_cw = (const float*)d_in[1];
    const float* g_cw = (const float*)d_in[2];
    const float* b_cw = (const float*)d_in[3];
    const float* m_cw = (const float*)d_in[4];
    const float* v_cw = (const float*)d_in[5];
    const float* w_hc = (const float*)d_in[6];
    const float* g_hc = (const float*)d_in[7];
    const float* b_hc = (const float*)d_in[8];
    const float* m_hc = (const float*)d_in[9];
    const float* v_hc = (const float*)d_in[10];
    const float* w_hw = (const float*)d_in[11];
    const float* g_hw = (const float*)d_in[12];
    const float* b_hw = (const float*)d_in[13];
    const float* m_hw = (const float*)d_in[14];
    const float* v_hw = (const float*)d_in[15];
    const float* w1d  = (const float*)d_in[16];
    float* out = (float*)d_out;

    // Workspace layout (floats)
    float* ws = (float*)d_ws;
    const size_t N1 = (size_t)BB * CC * WW;   // 131072  z1/s1 [B,C,W]
    const size_t N2 = (size_t)BB * HH * CC;   // 131072  z2/s2 [B,H,C]
    const size_t N3 = (size_t)BB * HH * WW;   // 32768   z3/s3 [B,H,W]
    float* z1max  = ws;
    float* z1mean = z1max  + N1;
    float* z2max  = z1mean + N1;
    float* z2mean = z2max  + N2;
    float* z3max  = z2mean + N2;
    float* z3mean = z3max  + N3;
    float* s1     = z3mean + N3;
    float* s2     = s1 + N1;
    float* s3     = s2 + N2;
    float* pooled = s3 + N3;                  // B*C = 2048

    pool_kernel<<<BB * CC + BB * HH, 256, 0, stream>>>(
        x, z1max, z1mean, z2max, z2mean, z3max, z3mean);

    conv_gate_kernel<<<dim3((BB * CC * WW + 255) / 256, 3), 256, 0, stream>>>(
        z1max, z1mean, w_cw, g_cw, b_cw, m_cw, v_cw, s1,
        z2max, z2mean, w_hc, g_hc, b_hc, m_hc, v_hc, s2,
        z3max, z3mean, w_hw, g_hw, b_hw, m_hw, v_hw, s3);

    pooled_kernel<<<BB * CC, 256, 0, stream>>>(
        x, s1, z1mean, s2, z2mean, s3, pooled);

    final_kernel<<<(BB * CC * HH * WW / 4) / 256, 256, 0, stream>>>(
        x, s1, s2, s3, pooled, w1d, out);
}